// Round 1
// baseline (514.275 us; speedup 1.0000x reference)
//
#include <hip/hip_runtime.h>
#include <hip/hip_bf16.h>

#define NSITES 100000
#define KOFFS 27
#define CIN 64
#define COUT 128

typedef unsigned short u16;
typedef __attribute__((ext_vector_type(8))) short s16x8;
typedef __attribute__((ext_vector_type(4))) float f32x4;

static __device__ __forceinline__ u16 f2bf(float f) {
    union { float f; unsigned u; } x; x.f = f;
    return (u16)((x.u + 0x7FFFu + ((x.u >> 16) & 1u)) >> 16);
}

// ---------- prep: transpose/convert weights to bf16 [k][d][c], zero stat partials ----------
__global__ void prep_kernel(const float* __restrict__ W1, const float* __restrict__ W2,
                            const float* __restrict__ Wsk,
                            u16* __restrict__ W1t, u16* __restrict__ W2t,
                            u16* __restrict__ Wskt, float* __restrict__ zero_area) {
    int i = blockIdx.x * 256 + threadIdx.x;
    if (i < 27 * 64 * 128) {
        int k = i / 8192, r = i & 8191, d = r >> 6, c = r & 63;
        W1t[i] = f2bf(W1[k * 8192 + c * 128 + d]);
        return;
    }
    i -= 27 * 64 * 128;
    if (i < 27 * 128 * 128) {
        int k = i / 16384, r = i & 16383, d = r >> 7, c = r & 127;
        W2t[i] = f2bf(W2[k * 16384 + c * 128 + d]);
        return;
    }
    i -= 27 * 128 * 128;
    if (i < 8192) {
        int d = i >> 6, c = i & 63;
        Wskt[i] = f2bf(Wsk[c * 128 + d]);
        return;
    }
    i -= 8192;
    zero_area[i] = 0.0f;  // 4 * 64*128 partial-stat floats
}

// ---------- x (fp32) -> bf16 rows, plus zero sentinel row N ----------
__global__ void convert_x_kernel(const float* __restrict__ x, u16* __restrict__ xb) {
    long long e = ((long long)blockIdx.x * 256 + threadIdx.x) * 8;
    if (e >= (long long)(NSITES + 1) * CIN) return;
    s16x8 o;
    if (e < (long long)NSITES * CIN) {
        float4 v0 = *(const float4*)(x + e);
        float4 v1 = *(const float4*)(x + e + 4);
        o[0] = (short)f2bf(v0.x); o[1] = (short)f2bf(v0.y);
        o[2] = (short)f2bf(v0.z); o[3] = (short)f2bf(v0.w);
        o[4] = (short)f2bf(v1.x); o[5] = (short)f2bf(v1.y);
        o[6] = (short)f2bf(v1.z); o[7] = (short)f2bf(v1.w);
    } else {
#pragma unroll
        for (int j = 0; j < 8; ++j) o[j] = 0;
    }
    *(s16x8*)(xb + e) = o;
}

// ---------- gather-GEMM conv: y[n0+r, :] = sum_k xin[nbr[r,k]] @ Wt[k]^T ----------
// Wt layout: [nk][COUT][CK] bf16 (pre-transposed, k-contiguous)
// Block: 256 thr = 4 waves, 64-row tile; wave w owns output cols [32w, 32w+32).
template <int CK, bool IDENT, bool STATS>
__global__ __launch_bounds__(256, 3) void conv_kernel(
    const u16* __restrict__ xin, const int* __restrict__ nbr,
    const u16* __restrict__ Wt, float* __restrict__ yout,
    float* __restrict__ psum, float* __restrict__ psq, int nk) {
    constexpr int STRIDE = CK + 8;   // +8 bf16 pad: row stride = 4 banks mod 32 -> 2-way (free)
    constexpr int KSTEPS = CK / 32;
    constexpr int CPR = CK / 8;      // 16B chunks per row
    constexpr int RPP = 256 / CPR;   // rows staged per pass
    __shared__ __align__(16) u16 a_tile[64 * STRIDE];
    __shared__ int nbr_tile[IDENT ? 64 : 64 * KOFFS];

    const int tid = threadIdx.x;
    const int wave = tid >> 6;
    const int lane = tid & 63;
    const int m = lane & 15;
    const int q = lane >> 4;
    const int n0 = blockIdx.x * 64;
    const int wc = wave * 32;

    if (!IDENT) {
        for (int i = tid; i < 64 * KOFFS; i += 256) {
            int r = i / KOFFS;
            int kk = i - r * KOFFS;
            int row = n0 + r;
            nbr_tile[i] = (row < NSITES) ? nbr[row * KOFFS + kk] : NSITES;
        }
    }

    f32x4 acc[4][2];
#pragma unroll
    for (int rt = 0; rt < 4; ++rt)
#pragma unroll
        for (int ct = 0; ct < 2; ++ct)
#pragma unroll
            for (int r = 0; r < 4; ++r) acc[rt][ct][r] = 0.0f;

    const int srow = tid / CPR;
    const int schunk = tid % CPR;

    for (int k = 0; k < nk; ++k) {
        // Prefetch B fragments for this offset (global, L2-hot; lands during staging+barrier)
        s16x8 bfrag[2][KSTEPS];
        const u16* wb = Wt + (long long)k * (COUT * CK);
#pragma unroll
        for (int ct = 0; ct < 2; ++ct)
#pragma unroll
            for (int ks = 0; ks < KSTEPS; ++ks) {
                int n = wc + ct * 16 + m;
                bfrag[ct][ks] = *(const s16x8*)(wb + n * CK + ks * 32 + q * 8);
            }

        __syncthreads();  // previous iter's LDS reads done (also covers nbr_tile on k=0)
#pragma unroll
        for (int p = 0; p < 64 / RPP; ++p) {
            int r = p * RPP + srow;
            int row = n0 + r;
            int idx;
            if (IDENT) idx = (row < NSITES) ? row : NSITES;
            else       idx = (row < NSITES) ? nbr_tile[r * KOFFS + k] : NSITES;
            s16x8 v = *(const s16x8*)(xin + (long long)idx * CK + schunk * 8);
            *(s16x8*)(a_tile + r * STRIDE + schunk * 8) = v;
        }
        __syncthreads();

#pragma unroll
        for (int ks = 0; ks < KSTEPS; ++ks) {
            s16x8 af[4];
#pragma unroll
            for (int rt = 0; rt < 4; ++rt)
                af[rt] = *(const s16x8*)(a_tile + (rt * 16 + m) * STRIDE + ks * 32 + q * 8);
#pragma unroll
            for (int rt = 0; rt < 4; ++rt)
#pragma unroll
                for (int ct = 0; ct < 2; ++ct)
                    acc[rt][ct] = __builtin_amdgcn_mfma_f32_16x16x32_bf16(
                        af[rt], bfrag[ct][ks], acc[rt][ct], 0, 0, 0);
        }
    }

    // Store y: C/D layout col=lane&15, row=(lane>>4)*4+reg  [m89-verified]
#pragma unroll
    for (int rt = 0; rt < 4; ++rt) {
        int rowb = n0 + rt * 16 + q * 4;
#pragma unroll
        for (int ct = 0; ct < 2; ++ct) {
            int col = wc + ct * 16 + m;
#pragma unroll
            for (int r = 0; r < 4; ++r) {
                int row = rowb + r;
                if (row < NSITES) yout[(long long)row * COUT + col] = acc[rt][ct][r];
            }
        }
    }

    if (STATS) {
#pragma unroll
        for (int ct = 0; ct < 2; ++ct) {
            float s = 0.f, ss = 0.f;
#pragma unroll
            for (int rt = 0; rt < 4; ++rt)
#pragma unroll
                for (int r = 0; r < 4; ++r) {
                    float v = acc[rt][ct][r];
                    s += v; ss += v * v;
                }
            s += __shfl_xor(s, 16); ss += __shfl_xor(ss, 16);
            s += __shfl_xor(s, 32); ss += __shfl_xor(ss, 32);
            if (q == 0) {  // one lane per column per block
                int col = wc + ct * 16 + m;
                int slot = blockIdx.x & 63;  // 64-slot tree cuts atomic contention ~24x
                atomicAdd(psum + slot * COUT + col, s);
                atomicAdd(psq + slot * COUT + col, ss);
            }
        }
    }
}

// ---------- reduce 64 slots -> per-column affine (a = gamma*rsqrt(var+eps), b = beta - mu*a) ----------
__global__ void bn_stats_kernel(const float* __restrict__ psum, const float* __restrict__ psq,
                                const float* __restrict__ gamma, const float* __restrict__ beta,
                                float* __restrict__ ab) {
    int col = threadIdx.x;  // 128 threads
    float s = 0.f, ss = 0.f;
    for (int i = 0; i < 64; ++i) { s += psum[i * COUT + col]; ss += psq[i * COUT + col]; }
    const float inv_n = 1.0f / (float)NSITES;
    float mu = s * inv_n;
    float var = ss * inv_n - mu * mu;
    float rs = rsqrtf(var + 1e-5f);
    float a = gamma[col] * rs;
    ab[col] = a;
    ab[COUT + col] = beta[col] - mu * a;
}

// ---------- h = bf16(relu(y*a+b)), plus zero sentinel row ----------
__global__ void bn_apply_kernel(const float* __restrict__ y, const float* __restrict__ ab,
                                u16* __restrict__ h) {
    long long e = ((long long)blockIdx.x * 256 + threadIdx.x) * 8;
    if (e >= (long long)(NSITES + 1) * COUT) return;
    s16x8 o;
    if (e < (long long)NSITES * COUT) {
        int cb = (int)(e & (COUT - 1));
        float4 v0 = *(const float4*)(y + e);
        float4 v1 = *(const float4*)(y + e + 4);
        float vs[8] = {v0.x, v0.y, v0.z, v0.w, v1.x, v1.y, v1.z, v1.w};
#pragma unroll
        for (int j = 0; j < 8; ++j) {
            float r = vs[j] * ab[cb + j] + ab[COUT + cb + j];
            o[j] = (short)f2bf(fmaxf(r, 0.f));
        }
    } else {
#pragma unroll
        for (int j = 0; j < 8; ++j) o[j] = 0;
    }
    *(s16x8*)(h + e) = o;
}

// ---------- out = relu(y*a+b) + identity (identity already resident in d_out) ----------
__global__ void final_kernel(const float* __restrict__ y, const float* __restrict__ ab,
                             float* __restrict__ out) {
    long long e = ((long long)blockIdx.x * 256 + threadIdx.x) * 8;
    if (e >= (long long)NSITES * COUT) return;
    int cb = (int)(e & (COUT - 1));
    float4 v0 = *(const float4*)(y + e);
    float4 v1 = *(const float4*)(y + e + 4);
    float4 i0 = *(const float4*)(out + e);
    float4 i1 = *(const float4*)(out + e + 4);
    float vs[8] = {v0.x, v0.y, v0.z, v0.w, v1.x, v1.y, v1.z, v1.w};
    float is[8] = {i0.x, i0.y, i0.z, i0.w, i1.x, i1.y, i1.z, i1.w};
    float os[8];
#pragma unroll
    for (int j = 0; j < 8; ++j) {
        float r = vs[j] * ab[cb + j] + ab[COUT + cb + j];
        os[j] = fmaxf(r, 0.f) + is[j];
    }
    *(float4*)(out + e) = make_float4(os[0], os[1], os[2], os[3]);
    *(float4*)(out + e + 4) = make_float4(os[4], os[5], os[6], os[7]);
}

extern "C" void kernel_launch(void* const* d_in, const int* in_sizes, int n_in,
                              void* d_out, int out_size, void* d_ws, size_t ws_size,
                              hipStream_t stream) {
    const float* x   = (const float*)d_in[0];
    const int*   nbr = (const int*)d_in[1];
    const float* W1  = (const float*)d_in[2];
    const float* g1  = (const float*)d_in[3];
    const float* b1  = (const float*)d_in[4];
    const float* W2  = (const float*)d_in[5];
    const float* g2  = (const float*)d_in[6];
    const float* b2  = (const float*)d_in[7];
    const float* Wsk = (const float*)d_in[8];
    float* out = (float*)d_out;

    // workspace layout (bytes, all 16B-aligned); total ~91 MB
    char* ws = (char*)d_ws;
    u16*   xb   = (u16*)(ws);                    // (N+1)*64 bf16      = 12,800,128 B
    u16*   W1t  = (u16*)(ws + 12800128);         // 27*128*64 bf16     =    442,368 B
    u16*   W2t  = (u16*)(ws + 13242496);         // 27*128*128 bf16    =    884,736 B
    u16*   Wskt = (u16*)(ws + 14127232);         // 128*64 bf16        =     16,384 B
    float* y    = (float*)(ws + 14143616);       // N*128 f32          = 51,200,000 B
    u16*   h1   = (u16*)(ws + 65343616);         // (N+1)*128 bf16     = 25,600,256 B
    float* ps1  = (float*)(ws + 90943872);       // 4 * 64*128 f32 partials
    float* pq1  = ps1 + 8192;
    float* ps2  = pq1 + 8192;
    float* pq2  = ps2 + 8192;
    float* ab1  = pq2 + 8192;                    // 2*256 f32 affine params
    float* ab2  = ab1 + 256;

    const int NBLK = (NSITES + 63) / 64;  // 1563

    prep_kernel<<<2752, 256, 0, stream>>>(W1, W2, Wsk, W1t, W2t, Wskt, ps1);
    convert_x_kernel<<<3126, 256, 0, stream>>>(x, xb);
    // identity = x @ W_skip -> d_out (fp32)
    conv_kernel<64, true, false><<<NBLK, 256, 0, stream>>>(xb, nullptr, Wskt, out, nullptr, nullptr, 1);
    // conv1 + fused stats
    conv_kernel<64, false, true><<<NBLK, 256, 0, stream>>>(xb, nbr, W1t, y, ps1, pq1, KOFFS);
    bn_stats_kernel<<<1, 128, 0, stream>>>(ps1, pq1, g1, b1, ab1);
    bn_apply_kernel<<<6251, 256, 0, stream>>>(y, ab1, h1);
    // conv2 + fused stats (reuses y buffer)
    conv_kernel<128, false, true><<<NBLK, 256, 0, stream>>>(h1, nbr, W2t, y, ps2, pq2, KOFFS);
    bn_stats_kernel<<<1, 128, 0, stream>>>(ps2, pq2, g2, b2, ab2);
    final_kernel<<<6250, 256, 0, stream>>>(y, ab2, out);
}

// Round 2
// 456.056 us; speedup vs baseline: 1.1277x; 1.1277x over previous
//
#include <hip/hip_runtime.h>
#include <hip/hip_bf16.h>

#define NSITES 100000
#define KOFFS 27
#define CIN 64
#define COUT 128

typedef unsigned short u16;
typedef __attribute__((ext_vector_type(8))) short s16x8;
typedef __attribute__((ext_vector_type(4))) float f32x4;

static __device__ __forceinline__ u16 f2bf(float f) {
    union { float f; unsigned u; } x; x.f = f;
    return (u16)((x.u + 0x7FFFu + ((x.u >> 16) & 1u)) >> 16);
}
static __device__ __forceinline__ float bf2f(u16 v) {
    union { unsigned u; float f; } x; x.u = ((unsigned)v) << 16;
    return x.f;
}

// ---------- prep: transpose/convert weights to bf16 [k][d][c], zero stat partials ----------
__global__ void prep_kernel(const float* __restrict__ W1, const float* __restrict__ W2,
                            const float* __restrict__ Wsk,
                            u16* __restrict__ W1t, u16* __restrict__ W2t,
                            u16* __restrict__ Wskt, float* __restrict__ zero_area) {
    int i = blockIdx.x * 256 + threadIdx.x;
    if (i < 27 * 64 * 128) {
        int k = i / 8192, r = i & 8191, d = r >> 6, c = r & 63;
        W1t[i] = f2bf(W1[k * 8192 + c * 128 + d]);
        return;
    }
    i -= 27 * 64 * 128;
    if (i < 27 * 128 * 128) {
        int k = i / 16384, r = i & 16383, d = r >> 7, c = r & 127;
        W2t[i] = f2bf(W2[k * 16384 + c * 128 + d]);
        return;
    }
    i -= 27 * 128 * 128;
    if (i < 8192) {
        int d = i >> 6, c = i & 63;
        Wskt[i] = f2bf(Wsk[c * 128 + d]);
        return;
    }
    i -= 8192;
    zero_area[i] = 0.0f;  // 4 * 64*128 partial-stat floats
}

// ---------- x (fp32) -> bf16 rows, plus zero sentinel row N ----------
__global__ void convert_x_kernel(const float* __restrict__ x, u16* __restrict__ xb) {
    long long e = ((long long)blockIdx.x * 256 + threadIdx.x) * 8;
    if (e >= (long long)(NSITES + 1) * CIN) return;
    s16x8 o;
    if (e < (long long)NSITES * CIN) {
        float4 v0 = *(const float4*)(x + e);
        float4 v1 = *(const float4*)(x + e + 4);
        o[0] = (short)f2bf(v0.x); o[1] = (short)f2bf(v0.y);
        o[2] = (short)f2bf(v0.z); o[3] = (short)f2bf(v0.w);
        o[4] = (short)f2bf(v1.x); o[5] = (short)f2bf(v1.y);
        o[6] = (short)f2bf(v1.z); o[7] = (short)f2bf(v1.w);
    } else {
#pragma unroll
        for (int j = 0; j < 8; ++j) o[j] = 0;
    }
    *(s16x8*)(xb + e) = o;
}

// ---------- gather-GEMM conv with register-prefetch pipeline ----------
// y[n0+r, :] = sum_k xin[nbr[r,k]] @ Wt[k]^T ; Wt layout [nk][COUT][CK] bf16.
// Block: 256 thr = 4 waves, 64-row tile; wave w owns output cols [32w, 32w+32).
// Pipeline: gathers for k+2 issued during iter k (hidden under 2 iters of MFMA+barriers);
// B-frags for k issued at loop-top (L2-hot W, hidden under ds_write+barrier).
template <int CK, bool IDENT_FUSE, bool STATS>
__global__ __launch_bounds__(256, 3) void conv_kernel(
    const u16* __restrict__ xin, const int* __restrict__ nbr,
    const u16* __restrict__ Wt, u16* __restrict__ yout,
    float* __restrict__ psum, float* __restrict__ psq, int nk,
    const u16* __restrict__ Wskt, float* __restrict__ outid) {
    constexpr int STRIDE = CK + 8;   // +8 bf16 pad -> 2-way bank aliasing (free, m136)
    constexpr int KSTEPS = CK / 32;
    constexpr int CPR = CK / 8;      // 16B chunks per row
    constexpr int RPP = 256 / CPR;   // rows staged per pass
    constexpr int NPASS = 64 / RPP;
    __shared__ __align__(16) u16 a_tile[64 * STRIDE];
    __shared__ int nbr_tile[64 * KOFFS];

    const int tid = threadIdx.x;
    const int wave = tid >> 6;
    const int lane = tid & 63;
    const int m = lane & 15;
    const int q = lane >> 4;
    const int n0 = blockIdx.x * 64;
    const int wc = wave * 32;
    const int srow = tid / CPR;
    const int schunk = tid % CPR;

    for (int i = tid; i < 64 * KOFFS; i += 256) {
        int r = i / KOFFS;
        int kk = i - r * KOFFS;
        int row = n0 + r;
        nbr_tile[i] = (row < NSITES) ? nbr[row * KOFFS + kk] : NSITES;
    }
    __syncthreads();

    f32x4 acc[4][2];
#pragma unroll
    for (int rt = 0; rt < 4; ++rt)
#pragma unroll
        for (int ct = 0; ct < 2; ++ct)
#pragma unroll
            for (int r = 0; r < 4; ++r) acc[rt][ct][r] = 0.0f;

    // prologue: issue gathers for k=0 and k=1 into two register sets
    s16x8 ag0[NPASS], ag1[NPASS];
#pragma unroll
    for (int p = 0; p < NPASS; ++p) {
        int r = p * RPP + srow;
        ag0[p] = *(const s16x8*)(xin + (long long)nbr_tile[r * KOFFS] * CK + schunk * 8);
    }
    if (nk > 1) {
#pragma unroll
        for (int p = 0; p < NPASS; ++p) {
            int r = p * RPP + srow;
            ag1[p] = *(const s16x8*)(xin + (long long)nbr_tile[r * KOFFS + 1] * CK + schunk * 8);
        }
    }

    auto conv_iter = [&](int k, s16x8 (&agc)[NPASS]) {
        // B fragments for this k (same addrs for all blocks -> L2-hot)
        s16x8 bf[2][KSTEPS];
        const u16* wb = Wt + (long long)k * (COUT * CK);
#pragma unroll
        for (int ct = 0; ct < 2; ++ct)
#pragma unroll
            for (int ks = 0; ks < KSTEPS; ++ks)
                bf[ct][ks] = *(const s16x8*)(wb + (wc + ct * 16 + m) * CK + ks * 32 + q * 8);

        // write prefetched A regs -> LDS (a_tile free per trailing barrier of prev iter)
#pragma unroll
        for (int p = 0; p < NPASS; ++p)
            *(s16x8*)(a_tile + (p * RPP + srow) * STRIDE + schunk * 8) = agc[p];

        // issue gathers for k+2 (consumed 2 iterations from now)
        if (k + 2 < nk) {
#pragma unroll
            for (int p = 0; p < NPASS; ++p) {
                int r = p * RPP + srow;
                agc[p] = *(const s16x8*)(xin + (long long)nbr_tile[r * KOFFS + k + 2] * CK + schunk * 8);
            }
        }
        __syncthreads();  // a_tile ready

#pragma unroll
        for (int ks = 0; ks < KSTEPS; ++ks) {
            s16x8 af[4];
#pragma unroll
            for (int rt = 0; rt < 4; ++rt)
                af[rt] = *(const s16x8*)(a_tile + (rt * 16 + m) * STRIDE + ks * 32 + q * 8);
#pragma unroll
            for (int rt = 0; rt < 4; ++rt)
#pragma unroll
                for (int ct = 0; ct < 2; ++ct)
                    acc[rt][ct] = __builtin_amdgcn_mfma_f32_16x16x32_bf16(
                        af[rt], bf[ct][ks], acc[rt][ct], 0, 0, 0);
        }
        __syncthreads();  // MFMA reads done before next iter's writes
    };

    for (int k = 0; k < nk; k += 2) {
        conv_iter(k, ag0);
        if (k + 1 < nk) conv_iter(k + 1, ag1);  // uniform branch: barrier inside is safe
    }

    // Store y (bf16): C/D layout col=lane&15, row=(lane>>4)*4+reg  [m89-verified]
#pragma unroll
    for (int rt = 0; rt < 4; ++rt) {
        int rowb = n0 + rt * 16 + q * 4;
#pragma unroll
        for (int ct = 0; ct < 2; ++ct) {
            int col = wc + ct * 16 + m;
#pragma unroll
            for (int r = 0; r < 4; ++r) {
                int row = rowb + r;
                if (row < NSITES) yout[(long long)row * COUT + col] = f2bf(acc[rt][ct][r]);
            }
        }
    }

    if (STATS) {
#pragma unroll
        for (int ct = 0; ct < 2; ++ct) {
            float s = 0.f, ss = 0.f;
#pragma unroll
            for (int rt = 0; rt < 4; ++rt)
#pragma unroll
                for (int r = 0; r < 4; ++r) {
                    float v = acc[rt][ct][r];
                    s += v; ss += v * v;
                }
            s += __shfl_xor(s, 16); ss += __shfl_xor(ss, 16);
            s += __shfl_xor(s, 32); ss += __shfl_xor(ss, 32);
            if (q == 0) {
                int col = wc + ct * 16 + m;
                int slot = blockIdx.x & 63;  // 64-slot tree cuts atomic contention
                atomicAdd(psum + slot * COUT + col, s);
                atomicAdd(psq + slot * COUT + col, ss);
            }
        }
    }

    if (IDENT_FUSE) {
        // identity = x @ W_skip for the same 64 rows (no gather); reuses acc regs
#pragma unroll
        for (int rt = 0; rt < 4; ++rt)
#pragma unroll
            for (int ct = 0; ct < 2; ++ct)
#pragma unroll
                for (int r = 0; r < 4; ++r) acc[rt][ct][r] = 0.0f;
        s16x8 aid[NPASS];
#pragma unroll
        for (int p = 0; p < NPASS; ++p) {
            int row = n0 + p * RPP + srow;
            long long idx = (row < NSITES) ? row : NSITES;
            aid[p] = *(const s16x8*)(xin + idx * CK + schunk * 8);
        }
        s16x8 bfi[2][KSTEPS];
#pragma unroll
        for (int ct = 0; ct < 2; ++ct)
#pragma unroll
            for (int ks = 0; ks < KSTEPS; ++ks)
                bfi[ct][ks] = *(const s16x8*)(Wskt + (wc + ct * 16 + m) * CK + ks * 32 + q * 8);
        // trailing barrier of the main loop already guarantees a_tile is free
#pragma unroll
        for (int p = 0; p < NPASS; ++p)
            *(s16x8*)(a_tile + (p * RPP + srow) * STRIDE + schunk * 8) = aid[p];
        __syncthreads();
#pragma unroll
        for (int ks = 0; ks < KSTEPS; ++ks) {
            s16x8 af[4];
#pragma unroll
            for (int rt = 0; rt < 4; ++rt)
                af[rt] = *(const s16x8*)(a_tile + (rt * 16 + m) * STRIDE + ks * 32 + q * 8);
#pragma unroll
            for (int rt = 0; rt < 4; ++rt)
#pragma unroll
                for (int ct = 0; ct < 2; ++ct)
                    acc[rt][ct] = __builtin_amdgcn_mfma_f32_16x16x32_bf16(
                        af[rt], bfi[ct][ks], acc[rt][ct], 0, 0, 0);
        }
#pragma unroll
        for (int rt = 0; rt < 4; ++rt) {
            int rowb = n0 + rt * 16 + q * 4;
#pragma unroll
            for (int ct = 0; ct < 2; ++ct) {
                int col = wc + ct * 16 + m;
#pragma unroll
                for (int r = 0; r < 4; ++r) {
                    int row = rowb + r;
                    if (row < NSITES) outid[(long long)row * COUT + col] = acc[rt][ct][r];
                }
            }
        }
    }
}

// ---------- reduce 64 slots -> per-column affine (a = gamma*rsqrt(var+eps), b = beta - mu*a) ----------
__global__ void bn_stats_kernel(const float* __restrict__ psum, const float* __restrict__ psq,
                                const float* __restrict__ gamma, const float* __restrict__ beta,
                                float* __restrict__ ab) {
    int col = threadIdx.x;  // 128 threads
    float s = 0.f, ss = 0.f;
    for (int i = 0; i < 64; ++i) { s += psum[i * COUT + col]; ss += psq[i * COUT + col]; }
    const float inv_n = 1.0f / (float)NSITES;
    float mu = s * inv_n;
    float var = ss * inv_n - mu * mu;
    float rs = rsqrtf(var + 1e-5f);
    float a = gamma[col] * rs;
    ab[col] = a;
    ab[COUT + col] = beta[col] - mu * a;
}

// ---------- h = bf16(relu(y*a+b)), plus zero sentinel row; y is bf16 ----------
__global__ void bn_apply_kernel(const u16* __restrict__ y, const float* __restrict__ ab,
                                u16* __restrict__ h) {
    long long e = ((long long)blockIdx.x * 256 + threadIdx.x) * 8;
    if (e >= (long long)(NSITES + 1) * COUT) return;
    s16x8 o;
    if (e < (long long)NSITES * COUT) {
        int cb = (int)(e & (COUT - 1));
        s16x8 v = *(const s16x8*)(y + e);
#pragma unroll
        for (int j = 0; j < 8; ++j) {
            float r = bf2f((u16)v[j]) * ab[cb + j] + ab[COUT + cb + j];
            o[j] = (short)f2bf(fmaxf(r, 0.f));
        }
    } else {
#pragma unroll
        for (int j = 0; j < 8; ++j) o[j] = 0;
    }
    *(s16x8*)(h + e) = o;
}

// ---------- out = relu(y*a+b) + identity (identity resident in d_out); y is bf16 ----------
__global__ void final_kernel(const u16* __restrict__ y, const float* __restrict__ ab,
                             float* __restrict__ out) {
    long long e = ((long long)blockIdx.x * 256 + threadIdx.x) * 8;
    if (e >= (long long)NSITES * COUT) return;
    int cb = (int)(e & (COUT - 1));
    s16x8 v = *(const s16x8*)(y + e);
    float4 i0 = *(const float4*)(out + e);
    float4 i1 = *(const float4*)(out + e + 4);
    float is[8] = {i0.x, i0.y, i0.z, i0.w, i1.x, i1.y, i1.z, i1.w};
    float os[8];
#pragma unroll
    for (int j = 0; j < 8; ++j) {
        float r = bf2f((u16)v[j]) * ab[cb + j] + ab[COUT + cb + j];
        os[j] = fmaxf(r, 0.f) + is[j];
    }
    *(float4*)(out + e) = make_float4(os[0], os[1], os[2], os[3]);
    *(float4*)(out + e + 4) = make_float4(os[4], os[5], os[6], os[7]);
}

extern "C" void kernel_launch(void* const* d_in, const int* in_sizes, int n_in,
                              void* d_out, int out_size, void* d_ws, size_t ws_size,
                              hipStream_t stream) {
    const float* x   = (const float*)d_in[0];
    const int*   nbr = (const int*)d_in[1];
    const float* W1  = (const float*)d_in[2];
    const float* g1  = (const float*)d_in[3];
    const float* b1  = (const float*)d_in[4];
    const float* W2  = (const float*)d_in[5];
    const float* g2  = (const float*)d_in[6];
    const float* b2  = (const float*)d_in[7];
    const float* Wsk = (const float*)d_in[8];
    float* out = (float*)d_out;

    // workspace layout (bytes, 16B-aligned); total ~66 MB
    char* ws = (char*)d_ws;
    u16*   xb   = (u16*)(ws);                    // (N+1)*64 bf16      = 12,800,128 B
    u16*   W1t  = (u16*)(ws + 12800128);         // 27*128*64 bf16     =    442,368 B
    u16*   W2t  = (u16*)(ws + 13242496);         // 27*128*128 bf16    =    884,736 B
    u16*   Wskt = (u16*)(ws + 14127232);         // 128*64 bf16        =     16,384 B
    u16*   y    = (u16*)(ws + 14143616);         // N*128 bf16         = 25,600,000 B
    u16*   h1   = (u16*)(ws + 39743616);         // (N+1)*128 bf16     = 25,600,256 B
    float* ps1  = (float*)(ws + 65343872);       // 4 * 64*128 f32 partials
    float* pq1  = ps1 + 8192;
    float* ps2  = pq1 + 8192;
    float* pq2  = ps2 + 8192;
    float* ab1  = pq2 + 8192;                    // 2*2*128 f32 affine params
    float* ab2  = ab1 + 256;

    const int NBLK = (NSITES + 63) / 64;  // 1563

    prep_kernel<<<2752, 256, 0, stream>>>(W1, W2, Wsk, W1t, W2t, Wskt, ps1);
    convert_x_kernel<<<3126, 256, 0, stream>>>(x, xb);
    // conv1 + fused stats + fused identity (identity -> d_out)
    conv_kernel<64, true, true><<<NBLK, 256, 0, stream>>>(xb, nbr, W1t, y, ps1, pq1, KOFFS, Wskt, out);
    bn_stats_kernel<<<1, 128, 0, stream>>>(ps1, pq1, g1, b1, ab1);
    bn_apply_kernel<<<6251, 256, 0, stream>>>(y, ab1, h1);
    // conv2 + fused stats (reuses y buffer)
    conv_kernel<128, false, true><<<NBLK, 256, 0, stream>>>(h1, nbr, W2t, y, ps2, pq2, KOFFS, nullptr, nullptr);
    bn_stats_kernel<<<1, 128, 0, stream>>>(ps2, pq2, g2, b2, ab2);
    final_kernel<<<6250, 256, 0, stream>>>(y, ab2, out);
}